// Round 1
// baseline (2417.398 us; speedup 1.0000x reference)
//
#include <hip/hip_runtime.h>
#include <hip/hip_bf16.h>

#define NV 3
#define NPTS 32768
#define C2C 256
#define C3C 32
#define CINC 288
#define HH 128
#define WWW 128
#define DDD 32

typedef short bh8 __attribute__((ext_vector_type(8)));
typedef float fx4 __attribute__((ext_vector_type(4)));
typedef unsigned short us4 __attribute__((ext_vector_type(4)));

__device__ __forceinline__ float b2f(unsigned short u) {
    unsigned int x = ((unsigned int)u) << 16;
    return __uint_as_float(x);
}
__device__ __forceinline__ unsigned short f2b(float f) {
    unsigned int x = __float_as_uint(f);
    unsigned int r = (x + 0x7FFFu + ((x >> 16) & 1u)) >> 16;
    return (unsigned short)r;
}

// ---------------- weight f32 -> bf16 ----------------
__global__ void k_f2b(const float* __restrict__ src, unsigned short* __restrict__ dst, int n) {
    int i = blockIdx.x * 256 + threadIdx.x;
    if (i < n) dst[i] = f2b(src[i]);
}

// ---------------- img (V,C2,H,W) f32 -> (V,H,W,C2) bf16 ----------------
__global__ void k_timg(const float* __restrict__ in, unsigned short* __restrict__ out) {
    // grid: x = V*H, y = W/64, z = C2/64 ; 256 threads
    int v = blockIdx.x >> 7, y = blockIdx.x & 127;
    int x0 = blockIdx.y << 6, c0 = blockIdx.z << 6;
    __shared__ float t[64][65];
    int tx = threadIdx.x & 63, tg = threadIdx.x >> 6;
    const float* src = in + (((size_t)(v * C2C + c0) * HH + y) * WWW + x0);
#pragma unroll
    for (int i = 0; i < 16; i++) {
        int cl = tg * 16 + i;
        t[cl][tx] = src[(size_t)cl * (HH * WWW) + tx];
    }
    __syncthreads();
    unsigned short* dst = out + ((size_t)(v * HH + y) * WWW + x0) * C2C + c0;
#pragma unroll
    for (int i = 0; i < 16; i++) {
        int xl = tg * 16 + i;
        dst[(size_t)xl * C2C + tx] = f2b(t[tx][xl]);
    }
}

// ---------------- vol (V,C3,32,32,32) f32 -> (V,32768,C3) bf16 ----------------
__global__ void k_tvol(const float* __restrict__ in, unsigned short* __restrict__ out) {
    // grid: x = V, y = 32768/256 ; 256 threads
    int v = blockIdx.x;
    int s0 = blockIdx.y << 8;
    __shared__ float t[32][257];
    int tid = threadIdx.x;
    const float* src = in + (size_t)v * C3C * 32768 + s0;
#pragma unroll
    for (int c = 0; c < 32; c++) t[c][tid] = src[(size_t)c * 32768 + tid];
    __syncthreads();
    unsigned short* dst = out + ((size_t)v * 32768 + s0) * C3C;
    int c = tid & 31, sb = tid >> 5;
#pragma unroll
    for (int j = 0; j < 32; j++) {
        int sl = j * 8 + sb;
        dst[(size_t)sl * C3C + c] = f2b(t[c][sl]);
    }
}

// ---------------- sampler: bilinear(256ch) + trilinear(32ch) -> ptT[(v*Nk+i)][288] bf16 ----------------
__global__ void k_sample(const float* __restrict__ pts, const float* __restrict__ proj,
                         const unsigned short* __restrict__ imgT, const unsigned short* __restrict__ volT,
                         unsigned short* __restrict__ ptT, int n0, int Nk) {
    int i = blockIdx.x;
    int v = blockIdx.y;
    int n = n0 + i;
    int tid = threadIdx.x;
    unsigned short* dstRow = ptT + (size_t)(v * Nk + i) * CINC;
    if (tid < C2C) {
        float gx = proj[n * 2 + 0], gy = proj[n * 2 + 1];
        float ix = ((gx + 1.0f) * (float)WWW - 1.0f) * 0.5f;
        ix = fminf(fmaxf(ix, 0.0f), (float)(WWW - 1));
        float iy = ((gy + 1.0f) * (float)HH - 1.0f) * 0.5f;
        iy = fminf(fmaxf(iy, 0.0f), (float)(HH - 1));
        float x0f = floorf(ix), y0f = floorf(iy);
        float wx = ix - x0f, wy = iy - y0f;
        int x0 = (int)x0f, y0 = (int)y0f;
        int x1 = min(x0 + 1, WWW - 1), y1 = min(y0 + 1, HH - 1);
        const unsigned short* base = imgT + (size_t)v * HH * WWW * C2C;
        float v00 = b2f(base[((size_t)(y0 * WWW + x0)) * C2C + tid]);
        float v01 = b2f(base[((size_t)(y0 * WWW + x1)) * C2C + tid]);
        float v10 = b2f(base[((size_t)(y1 * WWW + x0)) * C2C + tid]);
        float v11 = b2f(base[((size_t)(y1 * WWW + x1)) * C2C + tid]);
        float r = v00 * (1.0f - wy) * (1.0f - wx) + v01 * (1.0f - wy) * wx +
                  v10 * wy * (1.0f - wx) + v11 * wy * wx;
        dstRow[tid] = f2b(r);
    } else if (tid < CINC) {
        int c = tid - C2C;
        float gx = pts[n * 3 + 0] * 2.0f, gy = pts[n * 3 + 1] * 2.0f, gz = pts[n * 3 + 2] * 2.0f;
        float ix = ((gx + 1.0f) * (float)DDD - 1.0f) * 0.5f;
        ix = fminf(fmaxf(ix, 0.0f), (float)(DDD - 1));
        float iy = ((gy + 1.0f) * (float)DDD - 1.0f) * 0.5f;
        iy = fminf(fmaxf(iy, 0.0f), (float)(DDD - 1));
        float iz = ((gz + 1.0f) * (float)DDD - 1.0f) * 0.5f;
        iz = fminf(fmaxf(iz, 0.0f), (float)(DDD - 1));
        float x0f = floorf(ix), y0f = floorf(iy), z0f = floorf(iz);
        float wx = ix - x0f, wy = iy - y0f, wz = iz - z0f;
        int x0 = (int)x0f, y0 = (int)y0f, z0 = (int)z0f;
        int x1 = min(x0 + 1, DDD - 1), y1 = min(y0 + 1, DDD - 1), z1 = min(z0 + 1, DDD - 1);
        const unsigned short* base = volT + (size_t)v * 32768 * C3C;
#define GV(zz, yy, xx) b2f(base[((size_t)(((zz)*32 + (yy)) * 32 + (xx))) * C3C + c])
        float r = GV(z0, y0, x0) * (1.0f - wz) * (1.0f - wy) * (1.0f - wx) +
                  GV(z0, y0, x1) * (1.0f - wz) * (1.0f - wy) * wx +
                  GV(z0, y1, x0) * (1.0f - wz) * wy * (1.0f - wx) +
                  GV(z0, y1, x1) * (1.0f - wz) * wy * wx +
                  GV(z1, y0, x0) * wz * (1.0f - wy) * (1.0f - wx) +
                  GV(z1, y0, x1) * wz * (1.0f - wy) * wx +
                  GV(z1, y1, x0) * wz * wy * (1.0f - wx) +
                  GV(z1, y1, x1) * wz * wy * wx;
#undef GV
        dstRow[tid] = f2b(r);
    }
}

// ---------------- GEMM: C[n][m] = lrelu( sum_k A[m][k]*B(k,n) + bias[m] ) ----------------
// A [M][K] bf16 (K=K1+K2), B1 [NC][K1], B2 [NC][K2] (optional), C [NC][M] bf16.
// block 256 thr: 2x2 waves; block tile M=128, N=64; wave tile 64x32 (4x2 frags of 16x16), K-step 32.
__global__ __launch_bounds__(256) void k_gemm(const unsigned short* __restrict__ A, int K,
                                              const unsigned short* __restrict__ B1, int K1,
                                              const unsigned short* __restrict__ B2, int K2,
                                              const float* __restrict__ bias,
                                              unsigned short* __restrict__ C, int M) {
    int tid = threadIdx.x;
    int w = tid >> 6, l = tid & 63;
    int la = l & 15, lg = l >> 4;
    int wm = w & 1, wn = w >> 1;
    int mBase = blockIdx.x * 128 + wm * 64;
    int nBase = blockIdx.y * 64 + wn * 32;

    fx4 acc[4][2];
#pragma unroll
    for (int mi = 0; mi < 4; mi++)
#pragma unroll
        for (int ni = 0; ni < 2; ni++) acc[mi][ni] = (fx4){0.f, 0.f, 0.f, 0.f};

    {
        const unsigned short* aB = A + (size_t)(mBase + la) * K + lg * 8;
        const unsigned short* bB = B1 + (size_t)(nBase + la) * K1 + lg * 8;
        for (int k0 = 0; k0 < K1; k0 += 32) {
            bh8 a[4], b[2];
#pragma unroll
            for (int mi = 0; mi < 4; mi++) a[mi] = *(const bh8*)(aB + (size_t)mi * 16 * K + k0);
#pragma unroll
            for (int ni = 0; ni < 2; ni++) b[ni] = *(const bh8*)(bB + (size_t)ni * 16 * K1 + k0);
#pragma unroll
            for (int mi = 0; mi < 4; mi++)
#pragma unroll
                for (int ni = 0; ni < 2; ni++)
                    acc[mi][ni] = __builtin_amdgcn_mfma_f32_16x16x32_bf16(a[mi], b[ni], acc[mi][ni], 0, 0, 0);
        }
    }
    if (B2 != nullptr) {
        const unsigned short* aB = A + (size_t)(mBase + la) * K + K1 + lg * 8;
        const unsigned short* bB = B2 + (size_t)(nBase + la) * K2 + lg * 8;
        for (int k0 = 0; k0 < K2; k0 += 32) {
            bh8 a[4], b[2];
#pragma unroll
            for (int mi = 0; mi < 4; mi++) a[mi] = *(const bh8*)(aB + (size_t)mi * 16 * K + k0);
#pragma unroll
            for (int ni = 0; ni < 2; ni++) b[ni] = *(const bh8*)(bB + (size_t)ni * 16 * K2 + k0);
#pragma unroll
            for (int mi = 0; mi < 4; mi++)
#pragma unroll
                for (int ni = 0; ni < 2; ni++)
                    acc[mi][ni] = __builtin_amdgcn_mfma_f32_16x16x32_bf16(a[mi], b[ni], acc[mi][ni], 0, 0, 0);
        }
    }

#pragma unroll
    for (int mi = 0; mi < 4; mi++) {
        int m0 = mBase + mi * 16 + lg * 4;
        fx4 bb = *(const fx4*)(bias + m0);
#pragma unroll
        for (int ni = 0; ni < 2; ni++) {
            int n = nBase + ni * 16 + la;
            us4 rv;
#pragma unroll
            for (int r = 0; r < 4; r++) {
                float x = acc[mi][ni][r] + bb[r];
                x = (x >= 0.0f) ? x : 0.2f * x;
                rv[r] = f2b(x);
            }
            *(us4*)(C + (size_t)n * M + m0) = rv;
        }
    }
}

// ---------------- head: mean over views, W4 dot, sigmoid ----------------
__global__ void k_head(const unsigned short* __restrict__ o3, const float* __restrict__ W4,
                       const float* __restrict__ b4, const int* __restrict__ mn_p,
                       float* __restrict__ out, int n0, int Nk, int level) {
    int i = blockIdx.x * 256 + threadIdx.x;
    if (i >= Nk) return;
    int mn = *mn_p;
    if (mn > NV) mn = NV;
    if (mn < 1) mn = 1;
    float s = 0.0f;
    for (int c = 0; c < 128; c++) {
        float f = 0.0f;
        for (int v = 0; v < mn; v++) f += b2f(o3[((size_t)(v * Nk + i)) * 128 + c]);
        s += W4[c] * f;
    }
    s = s / (float)mn + b4[0];
    out[(size_t)level * NPTS + n0 + i] = 1.0f / (1.0f + expf(-s));
}

extern "C" void kernel_launch(void* const* d_in, const int* in_sizes, int n_in,
                              void* d_out, int out_size, void* d_ws, size_t ws_size,
                              hipStream_t stream) {
    const float* pts = (const float*)d_in[0];
    const float* proj = (const float*)d_in[1];
    const float* img[2] = {(const float*)d_in[2], (const float*)d_in[3]};
    const float* vol[2] = {(const float*)d_in[4], (const float*)d_in[5]};
    const float* Wf[4] = {(const float*)d_in[6], (const float*)d_in[8], (const float*)d_in[10], (const float*)d_in[12]};
    const float* bf[4] = {(const float*)d_in[7], (const float*)d_in[9], (const float*)d_in[11], (const float*)d_in[13]};
    const float* W4 = (const float*)d_in[14];
    const float* b4 = (const float*)d_in[15];
    const int* mn = (const int*)d_in[16];
    float* out = (float*)d_out;

    const int Ksz[4] = {288, 1312, 800, 544};
    const int Msz[4] = {1024, 512, 256, 128};

    char* ws = (char*)d_ws;
    size_t off = 0;
    auto alloc = [&](size_t bytes) -> char* {
        char* p = ws + off;
        off = (off + bytes + 255) & ~(size_t)255;
        return p;
    };

    unsigned short* Wb[4];
    for (int i = 0; i < 4; i++) Wb[i] = (unsigned short*)alloc((size_t)Msz[i] * Ksz[i] * 2);
    unsigned short* imgT = (unsigned short*)alloc((size_t)NV * HH * WWW * C2C * 2);
    unsigned short* volT = (unsigned short*)alloc((size_t)NV * 32768 * C3C * 2);
    size_t fixed = off;

    // per-point chunk bytes: 3 views * 2B * (288+1024+512+256+128)
    const size_t perPt = (size_t)NV * 2 * (CINC + 1024 + 512 + 256 + 128);
    int Nk = NPTS;
    if (fixed + (size_t)Nk * perPt + 4096 > ws_size) {
        size_t avail = (ws_size > fixed + 4096) ? (ws_size - fixed - 4096) : 0;
        long nk = (long)(avail / perPt);
        nk = (nk / 64) * 64;
        if (nk < 64) nk = 64;
        if (nk > NPTS) nk = NPTS;
        Nk = (int)nk;
    }
    unsigned short* ptT = (unsigned short*)alloc((size_t)NV * Nk * CINC * 2);
    unsigned short* o0 = (unsigned short*)alloc((size_t)NV * Nk * 1024 * 2);
    unsigned short* o1 = (unsigned short*)alloc((size_t)NV * Nk * 512 * 2);
    unsigned short* o2 = (unsigned short*)alloc((size_t)NV * Nk * 256 * 2);
    unsigned short* o3 = (unsigned short*)alloc((size_t)NV * Nk * 128 * 2);

    // convert weights to bf16 (once per launch)
    for (int i = 0; i < 4; i++) {
        int n = Msz[i] * Ksz[i];
        k_f2b<<<(n + 255) / 256, 256, 0, stream>>>(Wf[i], Wb[i], n);
    }

    for (int lvl = 0; lvl < 2; lvl++) {
        k_timg<<<dim3(NV * HH, WWW / 64, C2C / 64), 256, 0, stream>>>(img[lvl], imgT);
        k_tvol<<<dim3(NV, 32768 / 256), 256, 0, stream>>>(vol[lvl], volT);
        for (int n0 = 0; n0 < NPTS; n0 += Nk) {
            int nk = NPTS - n0 < Nk ? NPTS - n0 : Nk;
            int NC = NV * nk;
            k_sample<<<dim3(nk, NV), 320, 0, stream>>>(pts, proj, imgT, volT, ptT, n0, nk);
            k_gemm<<<dim3(1024 / 128, NC / 64), 256, 0, stream>>>(Wb[0], 288, ptT, 288, nullptr, 0, bf[0], o0, 1024);
            k_gemm<<<dim3(512 / 128, NC / 64), 256, 0, stream>>>(Wb[1], 1312, ptT, 288, o0, 1024, bf[1], o1, 512);
            k_gemm<<<dim3(256 / 128, NC / 64), 256, 0, stream>>>(Wb[2], 800, ptT, 288, o1, 512, bf[2], o2, 256);
            k_gemm<<<dim3(128 / 128, NC / 64), 256, 0, stream>>>(Wb[3], 544, ptT, 288, o2, 256, bf[3], o3, 128);
            k_head<<<(nk + 255) / 256, 256, 0, stream>>>(o3, W4, b4, mn, out, n0, nk, lvl);
        }
    }
}

// Round 2
// 1185.733 us; speedup vs baseline: 2.0387x; 2.0387x over previous
//
#include <hip/hip_runtime.h>
#include <hip/hip_bf16.h>

#define NV 3
#define NPTS 32768
#define C2C 256
#define C3C 32
#define CINC 288
#define HH 128
#define WWW 128
#define DDD 32

typedef short bh8 __attribute__((ext_vector_type(8)));
typedef float fx4 __attribute__((ext_vector_type(4)));
typedef unsigned short us4 __attribute__((ext_vector_type(4)));

__device__ __forceinline__ float b2f(unsigned short u) {
    unsigned int x = ((unsigned int)u) << 16;
    return __uint_as_float(x);
}
__device__ __forceinline__ unsigned short f2b(float f) {
    unsigned int x = __float_as_uint(f);
    unsigned int r = (x + 0x7FFFu + ((x >> 16) & 1u)) >> 16;
    return (unsigned short)r;
}

__device__ __forceinline__ void gl2lds16(const unsigned short* g, unsigned short* l) {
    __builtin_amdgcn_global_load_lds(
        (const __attribute__((address_space(1))) unsigned int*)g,
        (__attribute__((address_space(3))) unsigned int*)l, 16, 0, 0);
}

// ---------------- weight f32 -> bf16 ----------------
__global__ void k_f2b(const float* __restrict__ src, unsigned short* __restrict__ dst, int n) {
    int i = blockIdx.x * 256 + threadIdx.x;
    if (i < n) dst[i] = f2b(src[i]);
}

// ---------------- img (V,C2,H,W) f32 -> (V,H,W,C2) bf16 ----------------
__global__ void k_timg(const float* __restrict__ in, unsigned short* __restrict__ out) {
    int v = blockIdx.x >> 7, y = blockIdx.x & 127;
    int x0 = blockIdx.y << 6, c0 = blockIdx.z << 6;
    __shared__ float t[64][65];
    int tx = threadIdx.x & 63, tg = threadIdx.x >> 6;
    const float* src = in + (((size_t)(v * C2C + c0) * HH + y) * WWW + x0);
#pragma unroll
    for (int i = 0; i < 16; i++) {
        int cl = tg * 16 + i;
        t[cl][tx] = src[(size_t)cl * (HH * WWW) + tx];
    }
    __syncthreads();
    unsigned short* dst = out + ((size_t)(v * HH + y) * WWW + x0) * C2C + c0;
#pragma unroll
    for (int i = 0; i < 16; i++) {
        int xl = tg * 16 + i;
        dst[(size_t)xl * C2C + tx] = f2b(t[tx][xl]);
    }
}

// ---------------- vol (V,C3,32,32,32) f32 -> (V,32768,C3) bf16 ----------------
__global__ void k_tvol(const float* __restrict__ in, unsigned short* __restrict__ out) {
    int v = blockIdx.x;
    int s0 = blockIdx.y << 8;
    __shared__ float t[32][257];
    int tid = threadIdx.x;
    const float* src = in + (size_t)v * C3C * 32768 + s0;
#pragma unroll
    for (int c = 0; c < 32; c++) t[c][tid] = src[(size_t)c * 32768 + tid];
    __syncthreads();
    unsigned short* dst = out + ((size_t)v * 32768 + s0) * C3C;
    int c = tid & 31, sb = tid >> 5;
#pragma unroll
    for (int j = 0; j < 32; j++) {
        int sl = j * 8 + sb;
        dst[(size_t)sl * C3C + c] = f2b(t[c][sl]);
    }
}

// ---------------- sampler: wave per (point,view) ----------------
__global__ __launch_bounds__(256) void k_sample(const float* __restrict__ pts, const float* __restrict__ proj,
                         const unsigned short* __restrict__ imgT, const unsigned short* __restrict__ volT,
                         unsigned short* __restrict__ ptT, int n0, int Nk) {
    int w = threadIdx.x >> 6, l = threadIdx.x & 63;
    int i = blockIdx.x * 4 + w;
    int v = blockIdx.y;
    int n = n0 + i;
    unsigned short* dstRow = ptT + (size_t)(v * Nk + i) * CINC;

    // ---- 2D bilinear, 256 channels: lane l -> ch 4l..4l+3 ----
    {
        float gx = proj[n * 2 + 0], gy = proj[n * 2 + 1];
        float ix = fminf(fmaxf(((gx + 1.0f) * (float)WWW - 1.0f) * 0.5f, 0.0f), (float)(WWW - 1));
        float iy = fminf(fmaxf(((gy + 1.0f) * (float)HH - 1.0f) * 0.5f, 0.0f), (float)(HH - 1));
        float x0f = floorf(ix), y0f = floorf(iy);
        float wx = ix - x0f, wy = iy - y0f;
        int x0 = (int)x0f, y0 = (int)y0f;
        int x1 = min(x0 + 1, WWW - 1), y1 = min(y0 + 1, HH - 1);
        const unsigned short* base = imgT + (size_t)v * HH * WWW * C2C;
        const us4* p00 = (const us4*)(base + ((size_t)(y0 * WWW + x0)) * C2C) + l;
        const us4* p01 = (const us4*)(base + ((size_t)(y0 * WWW + x1)) * C2C) + l;
        const us4* p10 = (const us4*)(base + ((size_t)(y1 * WWW + x0)) * C2C) + l;
        const us4* p11 = (const us4*)(base + ((size_t)(y1 * WWW + x1)) * C2C) + l;
        us4 a = *p00, b = *p01, c = *p10, d = *p11;
        float w00 = (1.0f - wy) * (1.0f - wx), w01 = (1.0f - wy) * wx;
        float w10 = wy * (1.0f - wx), w11 = wy * wx;
        us4 rv;
#pragma unroll
        for (int r = 0; r < 4; r++) {
            float f = b2f(a[r]) * w00 + b2f(b[r]) * w01 + b2f(c[r]) * w10 + b2f(d[r]) * w11;
            rv[r] = f2b(f);
        }
        *(us4*)(dstRow + l * 4) = rv;
    }
    // ---- 3D trilinear, 32 channels: lane = (c = l&31, zside = l>>5) ----
    {
        float gx = pts[n * 3 + 0] * 2.0f, gy = pts[n * 3 + 1] * 2.0f, gz = pts[n * 3 + 2] * 2.0f;
        float ix = fminf(fmaxf(((gx + 1.0f) * (float)DDD - 1.0f) * 0.5f, 0.0f), (float)(DDD - 1));
        float iy = fminf(fmaxf(((gy + 1.0f) * (float)DDD - 1.0f) * 0.5f, 0.0f), (float)(DDD - 1));
        float iz = fminf(fmaxf(((gz + 1.0f) * (float)DDD - 1.0f) * 0.5f, 0.0f), (float)(DDD - 1));
        float x0f = floorf(ix), y0f = floorf(iy), z0f = floorf(iz);
        float wx = ix - x0f, wy = iy - y0f, wz = iz - z0f;
        int x0 = (int)x0f, y0 = (int)y0f, z0 = (int)z0f;
        int x1 = min(x0 + 1, DDD - 1), y1 = min(y0 + 1, DDD - 1), z1 = min(z0 + 1, DDD - 1);
        int c = l & 31, zs = l >> 5;
        int zi = zs ? z1 : z0;
        float wzs = zs ? wz : (1.0f - wz);
        const unsigned short* base = volT + (size_t)v * 32768 * C3C;
        float f00 = b2f(base[((size_t)((zi * 32 + y0) * 32 + x0)) * C3C + c]);
        float f01 = b2f(base[((size_t)((zi * 32 + y0) * 32 + x1)) * C3C + c]);
        float f10 = b2f(base[((size_t)((zi * 32 + y1) * 32 + x0)) * C3C + c]);
        float f11 = b2f(base[((size_t)((zi * 32 + y1) * 32 + x1)) * C3C + c]);
        float r = (f00 * (1.0f - wy) * (1.0f - wx) + f01 * (1.0f - wy) * wx +
                   f10 * wy * (1.0f - wx) + f11 * wy * wx) * wzs;
        float other = __shfl_xor(r, 32);
        r += other;
        if (zs == 0) dstRow[C2C + c] = f2b(r);
    }
}

// ---------------- LDS-staged GEMM (m97 structure) ----------------
// C[n][m] = lrelu( sum_k A[m][k]*B(k,n) + bias[m] ), A [M][K] bf16, B1 [NC][K1], B2 [NC][K2].
// Block 128(M)x128(N), BK=32, 256 thr = 2x2 waves, wave tile 64x64 (4x4 16x16x32 frags).
__global__ __launch_bounds__(256) void k_gemm(const unsigned short* __restrict__ A, int K,
                                              const unsigned short* __restrict__ B1, int K1,
                                              const unsigned short* __restrict__ B2, int K2,
                                              const float* __restrict__ bias,
                                              unsigned short* __restrict__ C, int M) {
    __shared__ unsigned short As[128 * 32];
    __shared__ unsigned short Bs[128 * 32];
    int tid = threadIdx.x;
    int w = tid >> 6, l = tid & 63;
    int la = l & 15, lg = l >> 4;
    int wm = w & 1, wn = w >> 1;
    int mBlk = blockIdx.x * 128;
    int nBlk = blockIdx.y * 128;

    // staging: wave w covers rows [w*32, w*32+32); lane l -> row w*32 + j*16 + (l>>2), col (l&3)*8
    int sRow = l >> 2;
    int sCol = (l & 3) * 8;

    fx4 acc[4][4];
#pragma unroll
    for (int mi = 0; mi < 4; mi++)
#pragma unroll
        for (int ni = 0; ni < 4; ni++) acc[mi][ni] = (fx4){0.f, 0.f, 0.f, 0.f};

    const unsigned short* Ag = A + (size_t)mBlk * K;
    const unsigned short* Bg;

#define KLOOP(BPTR, KB, AOFF)                                                                  \
    Bg = (BPTR) + (size_t)nBlk * (KB);                                                         \
    for (int k0 = 0; k0 < (KB); k0 += 32) {                                                    \
        _Pragma("unroll")                                                                      \
        for (int j = 0; j < 2; j++) {                                                          \
            int r = w * 32 + j * 16 + sRow;                                                    \
            gl2lds16(Ag + (size_t)r * K + (AOFF) + k0 + sCol, &As[r * 32 + sCol]);             \
            gl2lds16(Bg + (size_t)r * (KB) + k0 + sCol, &Bs[r * 32 + sCol]);                   \
        }                                                                                      \
        __syncthreads();                                                                       \
        bh8 af[4], bf8[4];                                                                     \
        _Pragma("unroll")                                                                      \
        for (int mi = 0; mi < 4; mi++) af[mi] = *(const bh8*)&As[(wm * 64 + mi * 16 + la) * 32 + lg * 8]; \
        _Pragma("unroll")                                                                      \
        for (int ni = 0; ni < 4; ni++) bf8[ni] = *(const bh8*)&Bs[(wn * 64 + ni * 16 + la) * 32 + lg * 8]; \
        _Pragma("unroll")                                                                      \
        for (int mi = 0; mi < 4; mi++)                                                         \
            _Pragma("unroll")                                                                  \
            for (int ni = 0; ni < 4; ni++)                                                     \
                acc[mi][ni] = __builtin_amdgcn_mfma_f32_16x16x32_bf16(af[mi], bf8[ni], acc[mi][ni], 0, 0, 0); \
        __syncthreads();                                                                       \
    }

    KLOOP(B1, K1, 0)
    if (B2 != nullptr) {
        KLOOP(B2, K2, K1)
    }
#undef KLOOP

#pragma unroll
    for (int mi = 0; mi < 4; mi++) {
        int m0 = mBlk + wm * 64 + mi * 16 + lg * 4;
        fx4 bb = *(const fx4*)(bias + m0);
#pragma unroll
        for (int ni = 0; ni < 4; ni++) {
            int n = nBlk + wn * 64 + ni * 16 + la;
            us4 rv;
#pragma unroll
            for (int r = 0; r < 4; r++) {
                float x = acc[mi][ni][r] + bb[r];
                x = (x >= 0.0f) ? x : 0.2f * x;
                rv[r] = f2b(x);
            }
            *(us4*)(C + (size_t)n * M + m0) = rv;
        }
    }
}

// ---------------- head: mean over views, W4 dot, sigmoid ----------------
__global__ void k_head(const unsigned short* __restrict__ o3, const float* __restrict__ W4,
                       const float* __restrict__ b4, const int* __restrict__ mn_p,
                       float* __restrict__ out, int n0, int Nk, int level) {
    int i = blockIdx.x * 256 + threadIdx.x;
    if (i >= Nk) return;
    int mn = *mn_p;
    if (mn > NV) mn = NV;
    if (mn < 1) mn = 1;
    float s = 0.0f;
    for (int v = 0; v < mn; v++) {
        const unsigned short* row = o3 + (size_t)(v * Nk + i) * 128;
        for (int c0 = 0; c0 < 128; c0 += 8) {
            bh8 x = *(const bh8*)(row + c0);
#pragma unroll
            for (int r = 0; r < 8; r++) s += W4[c0 + r] * b2f((unsigned short)x[r]);
        }
    }
    s = s / (float)mn + b4[0];
    out[(size_t)level * NPTS + n0 + i] = 1.0f / (1.0f + expf(-s));
}

extern "C" void kernel_launch(void* const* d_in, const int* in_sizes, int n_in,
                              void* d_out, int out_size, void* d_ws, size_t ws_size,
                              hipStream_t stream) {
    const float* pts = (const float*)d_in[0];
    const float* proj = (const float*)d_in[1];
    const float* img[2] = {(const float*)d_in[2], (const float*)d_in[3]};
    const float* vol[2] = {(const float*)d_in[4], (const float*)d_in[5]};
    const float* Wf[4] = {(const float*)d_in[6], (const float*)d_in[8], (const float*)d_in[10], (const float*)d_in[12]};
    const float* bf[4] = {(const float*)d_in[7], (const float*)d_in[9], (const float*)d_in[11], (const float*)d_in[13]};
    const float* W4 = (const float*)d_in[14];
    const float* b4 = (const float*)d_in[15];
    const int* mn = (const int*)d_in[16];
    float* out = (float*)d_out;

    const int Ksz[4] = {288, 1312, 800, 544};
    const int Msz[4] = {1024, 512, 256, 128};

    char* ws = (char*)d_ws;
    size_t off = 0;
    auto alloc = [&](size_t bytes) -> char* {
        char* p = ws + off;
        off = (off + bytes + 255) & ~(size_t)255;
        return p;
    };

    unsigned short* Wb[4];
    for (int i = 0; i < 4; i++) Wb[i] = (unsigned short*)alloc((size_t)Msz[i] * Ksz[i] * 2);
    unsigned short* imgT = (unsigned short*)alloc((size_t)NV * HH * WWW * C2C * 2);
    unsigned short* volT = (unsigned short*)alloc((size_t)NV * 32768 * C3C * 2);
    size_t fixed = off;

    const size_t perPt = (size_t)NV * 2 * (CINC + 1024 + 512 + 256 + 128);
    int Nk = NPTS;
    if (fixed + (size_t)Nk * perPt + 4096 > ws_size) {
        size_t avail = (ws_size > fixed + 4096) ? (ws_size - fixed - 4096) : 0;
        long nk = (long)(avail / perPt);
        nk = (nk / 128) * 128;
        if (nk < 128) nk = 128;
        if (nk > NPTS) nk = NPTS;
        Nk = (int)nk;
    }
    unsigned short* ptT = (unsigned short*)alloc((size_t)NV * Nk * CINC * 2);
    unsigned short* o0 = (unsigned short*)alloc((size_t)NV * Nk * 1024 * 2);
    unsigned short* o1 = (unsigned short*)alloc((size_t)NV * Nk * 512 * 2);
    unsigned short* o2 = (unsigned short*)alloc((size_t)NV * Nk * 256 * 2);
    unsigned short* o3 = (unsigned short*)alloc((size_t)NV * Nk * 128 * 2);

    for (int i = 0; i < 4; i++) {
        int n = Msz[i] * Ksz[i];
        k_f2b<<<(n + 255) / 256, 256, 0, stream>>>(Wf[i], Wb[i], n);
    }

    for (int lvl = 0; lvl < 2; lvl++) {
        k_timg<<<dim3(NV * HH, WWW / 64, C2C / 64), 256, 0, stream>>>(img[lvl], imgT);
        k_tvol<<<dim3(NV, 32768 / 256), 256, 0, stream>>>(vol[lvl], volT);
        for (int n0 = 0; n0 < NPTS; n0 += Nk) {
            int nk = NPTS - n0 < Nk ? NPTS - n0 : Nk;
            int NC = NV * nk;
            k_sample<<<dim3(nk / 4, NV), 256, 0, stream>>>(pts, proj, imgT, volT, ptT, n0, nk);
            k_gemm<<<dim3(1024 / 128, NC / 128), 256, 0, stream>>>(Wb[0], 288, ptT, 288, nullptr, 0, bf[0], o0, 1024);
            k_gemm<<<dim3(512 / 128, NC / 128), 256, 0, stream>>>(Wb[1], 1312, ptT, 288, o0, 1024, bf[1], o1, 512);
            k_gemm<<<dim3(256 / 128, NC / 128), 256, 0, stream>>>(Wb[2], 800, ptT, 288, o1, 512, bf[2], o2, 256);
            k_gemm<<<dim3(128 / 128, NC / 128), 256, 0, stream>>>(Wb[3], 544, ptT, 288, o2, 256, bf[3], o3, 128);
            k_head<<<(nk + 255) / 256, 256, 0, stream>>>(o3, W4, b4, mn, out, n0, nk, lvl);
        }
    }
}